// Round 4
// baseline (14689.066 us; speedup 1.0000x reference)
//
#include <hip/hip_runtime.h>

// v4: same bitwise arithmetic as v3 (passed, absmax 8.179e-3), restructured for
// occupancy: 512-thread blocks, h streamed per 32-row k-tile (no hS[33][512]),
// W2 via global_load_lds dbuf. LDS ~76.6KB -> 2 blocks/CU; VGPR capped 128 ->
// 16 waves/CU (was 4).
//
// Chain model (unchanged): every dot = sequential ascending-k fmaf from 0;
// h@W2 (K=512) has one partial-sum boundary at k=384 (OpenBLAS KC); tanh via
// f64 rounded to f32; bias adds and +eye separate fp32 adds; FD divide by
// fl32(2e-4).

#define HH 512
#define DD 256
#define EPSF 1e-4f
#define TWOEPS (2.0f * 1e-4f)
#define NT 16      // 16 tiles x 32 k-rows
#define KT1 12     // tiles 0..11 -> segment-1 accumulator (k<384)
#define HB0 16384  // float offset of h double-buffer in SM
#define HSTR 1088  // per-half h size (33*32=1056, padded)

__global__ __launch_bounds__(512, 4)
void christoffel_mimic(const float* __restrict__ z,
                       const float* __restrict__ W1,
                       const float* __restrict__ b1,
                       const float* __restrict__ W2,
                       const float* __restrict__ b2,
                       float* __restrict__ out)
{
    // [0,8192) W2 buf0 | [8192,16384) W2 buf1 | [16384,18560) h dbuf
    // endgame overlay: A[33][256] at [0,8448); dg -> even A rows; T -> odd rows
    __shared__ __align__(16) float SM[18560];
    __shared__ float gaug[16 * 36];
    __shared__ float zS[16];

    const int tid  = threadIdx.x;
    const int pt   = blockIdx.x;
    const int wv   = tid >> 6;        // wave 0..7
    const int lane = tid & 63;
    const int c4   = lane * 4;        // 4 output cols per lane

    if (tid < 16) zS[tid] = z[pt * 16 + tid];
    __syncthreads();

    // ---- stage W2 tile tn (32 rows = contiguous 32KB) into buf tn&1
    auto stage_w2 = [&](int tn) {
        const char* g = (const char*)W2 + tn * 32768 + wv * 4096 + lane * 16;
        char* l = (char*)(&SM[(tn & 1) * 8192]) + wv * 4096;   // wave-uniform
        #pragma unroll
        for (int c = 0; c < 4; ++c)
            __builtin_amdgcn_global_load_lds(
                (const __attribute__((address_space(1))) void*)(g + c * 1024),
                (__attribute__((address_space(3))) void*)(l + c * 1024),
                16, 0, 0);
    };

    // ---- compute h for tile tn into h-buf tn&1 (bitwise v3 chains)
    auto compute_h = [&](int tn) {
        const int jloc = tid & 31;
        const int j = tn * 32 + jloc;
        float w1c[16];
        #pragma unroll
        for (int d = 0; d < 16; ++d) w1c[d] = W1[d * HH + j];
        const float b1v = b1[j];
        float* hw = &SM[HB0 + (tn & 1) * HSTR];
        const int e0 = tid >> 5;            // 0..15
        #pragma unroll
        for (int pass = 0; pass < 2; ++pass) {
            const int e = e0 + pass * 16;   // 0..31
            const int p = e >> 1;
            const float zb = zS[p];
            const float zp = (e & 1) ? (zb - EPSF) : (zb + EPSF);
            float a = 0.0f;
            #pragma unroll
            for (int d = 0; d < 16; ++d) {
                const float zd = (d == p) ? zp : zS[d];
                a = fmaf(zd, w1c[d], a);
            }
            a = a + b1v;
            hw[e * 32 + jloc] = (float)tanh((double)a);
        }
        if (tid < 32) {                     // central eval e=32
            float a = 0.0f;
            #pragma unroll
            for (int d = 0; d < 16; ++d) a = fmaf(zS[d], w1c[d], a);
            a = a + b1v;
            hw[32 * 32 + jloc] = (float)tanh((double)a);
        }
    };

    // ---- GEMM one 32-row tile into the given accumulators
    auto gemm_tile = [&](int t, float (&A)[4][4], float (&C)[4]) {
        const float* wb = &SM[(t & 1) * 8192];
        const float* hb = &SM[HB0 + (t & 1) * HSTR];
        const int r0 = wv * 4;
        #pragma unroll
        for (int q = 0; q < 8; ++q) {
            const float4 w0 = *(const float4*)&wb[(q * 4 + 0) * DD + c4];
            const float4 w1v = *(const float4*)&wb[(q * 4 + 1) * DD + c4];
            const float4 w2v = *(const float4*)&wb[(q * 4 + 2) * DD + c4];
            const float4 w3 = *(const float4*)&wb[(q * 4 + 3) * DD + c4];
            #pragma unroll
            for (int r = 0; r < 4; ++r) {
                const float4 hv = *(const float4*)&hb[(r0 + r) * 32 + q * 4];
                float* Ar = A[r];
                Ar[0]=fmaf(hv.x,w0.x,Ar[0]); Ar[1]=fmaf(hv.x,w0.y,Ar[1]); Ar[2]=fmaf(hv.x,w0.z,Ar[2]); Ar[3]=fmaf(hv.x,w0.w,Ar[3]);
                Ar[0]=fmaf(hv.y,w1v.x,Ar[0]); Ar[1]=fmaf(hv.y,w1v.y,Ar[1]); Ar[2]=fmaf(hv.y,w1v.z,Ar[2]); Ar[3]=fmaf(hv.y,w1v.w,Ar[3]);
                Ar[0]=fmaf(hv.z,w2v.x,Ar[0]); Ar[1]=fmaf(hv.z,w2v.y,Ar[1]); Ar[2]=fmaf(hv.z,w2v.z,Ar[2]); Ar[3]=fmaf(hv.z,w2v.w,Ar[3]);
                Ar[0]=fmaf(hv.w,w3.x,Ar[0]); Ar[1]=fmaf(hv.w,w3.y,Ar[1]); Ar[2]=fmaf(hv.w,w3.z,Ar[2]); Ar[3]=fmaf(hv.w,w3.w,Ar[3]);
            }
            if (wv == 7) {                  // central row
                const float4 hv = *(const float4*)&hb[32 * 32 + q * 4];
                C[0]=fmaf(hv.x,w0.x,C[0]); C[1]=fmaf(hv.x,w0.y,C[1]); C[2]=fmaf(hv.x,w0.z,C[2]); C[3]=fmaf(hv.x,w0.w,C[3]);
                C[0]=fmaf(hv.y,w1v.x,C[0]); C[1]=fmaf(hv.y,w1v.y,C[1]); C[2]=fmaf(hv.y,w1v.z,C[2]); C[3]=fmaf(hv.y,w1v.w,C[3]);
                C[0]=fmaf(hv.z,w2v.x,C[0]); C[1]=fmaf(hv.z,w2v.y,C[1]); C[2]=fmaf(hv.z,w2v.z,C[2]); C[3]=fmaf(hv.z,w2v.w,C[3]);
                C[0]=fmaf(hv.w,w3.x,C[0]); C[1]=fmaf(hv.w,w3.y,C[1]); C[2]=fmaf(hv.w,w3.z,C[2]); C[3]=fmaf(hv.w,w3.w,C[3]);
            }
        }
    };

    float a1[4][4] = {}, a2[4][4] = {}, c1[4] = {}, c2[4] = {};

    // prologue
    stage_w2(0);
    compute_h(0);
    __syncthreads();                        // drains vmcnt+lgkm: tile 0 ready

    #pragma unroll 1
    for (int t = 0; t < NT; ++t) {
        if (t + 1 < NT) { stage_w2(t + 1); compute_h(t + 1); }
        if (t < KT1) gemm_tile(t, a1, c1); else gemm_tile(t, a2, c2);
        __syncthreads();
    }

    // ---- A writeback: fl(S1+S2)+b2, rows = eval ids, A[row][256] at SM[0..]
    {
        const float4 b2v = *(const float4*)&b2[c4];
        #pragma unroll
        for (int r = 0; r < 4; ++r) {
            float4 av;
            av.x = (a1[r][0] + a2[r][0]) + b2v.x;
            av.y = (a1[r][1] + a2[r][1]) + b2v.y;
            av.z = (a1[r][2] + a2[r][2]) + b2v.z;
            av.w = (a1[r][3] + a2[r][3]) + b2v.w;
            *(float4*)&SM[(wv * 4 + r) * DD + c4] = av;
        }
        if (wv == 7) {
            float4 av;
            av.x = (c1[0] + c2[0]) + b2v.x;
            av.y = (c1[1] + c2[1]) + b2v.y;
            av.z = (c1[2] + c2[2]) + b2v.z;
            av.w = (c1[3] + c2[3]) + b2v.w;
            *(float4*)&SM[32 * DD + c4] = av;
        }
    }
    __syncthreads();

    // ---- central gram -> gaug = [g | I]
    if (tid < 256) {
        const int m = tid >> 4, n = tid & 15;
        const float* AC = &SM[32 * DD];
        float s = 0.0f;
        #pragma unroll
        for (int k = 0; k < 16; ++k) s = fmaf(AC[m * 16 + k], AC[n * 16 + k], s);
        if (m == n) s = s + 1.0f;
        gaug[m * 36 + n]      = s;
        gaug[m * 36 + 16 + n] = (m == n) ? 1.0f : 0.0f;
    }

    // ---- dg[p] = (gram(A2p)-gram(A2p+1))/2eps, written in place over row 2p.
    // Two p's at once (thread halves); reads {4pp+2ph, +1}, writes 4pp+2ph.
    {
        const int ph = tid >> 8, m = (tid >> 4) & 15, n = tid & 15;
        #pragma unroll 1
        for (int pp = 0; pp < 8; ++pp) {
            const int p = pp * 2 + ph;
            const float* Ap = &SM[(2 * p) * DD];
            const float* Am = &SM[(2 * p + 1) * DD];
            float sp = 0.0f, sm = 0.0f;
            #pragma unroll
            for (int k = 0; k < 16; ++k) sp = fmaf(Ap[m * 16 + k], Ap[n * 16 + k], sp);
            #pragma unroll
            for (int k = 0; k < 16; ++k) sm = fmaf(Am[m * 16 + k], Am[n * 16 + k], sm);
            if (m == n) { sp = sp + 1.0f; sm = sm + 1.0f; }
            const float dgv = (sp - sm) / TWOEPS;
            __syncthreads();                 // all reads done before in-place write
            SM[(2 * p) * DD + m * 16 + n] = dgv;
        }
    }
    __syncthreads();

    // ---- Gauss-Jordan inverse of central g (512 thr: one col each)
    {
        const int i = tid >> 5, c = tid & 31;
        #pragma unroll 1
        for (int k = 0; k < 16; ++k) {
            const float pv = gaug[k * 36 + k];
            const float f  = gaug[i * 36 + k];
            const float rk = gaug[k * 36 + c];
            const float gi = gaug[i * 36 + c];
            __syncthreads();
            const float invp = 1.0f / pv;
            gaug[i * 36 + c] = (i == k) ? (rk * invp) : (gi - (f * invp) * rk);
            __syncthreads();
        }
    }

    // ---- T[i][j][m] = dg_i[j,m] + dg_j[i,m] - dg_m[i,j]  -> odd rows
    {
        const int i = tid >> 5, j = (tid >> 1) & 15, mh = (tid & 1) * 8;
        float tv[8];
        #pragma unroll
        for (int q = 0; q < 8; ++q) {
            const int m = mh + q;
            tv[q] = SM[(2 * i) * DD + j * 16 + m]
                  + SM[(2 * j) * DD + i * 16 + m]
                  - SM[(2 * m) * DD + i * 16 + j];
        }
        #pragma unroll
        for (int q = 0; q < 8; ++q)
            SM[(2 * i + 1) * DD + j * 16 + mh + q] = tv[q];   // disjoint from reads
    }
    __syncthreads();

    // ---- Gamma[k][i][j] = 0.5 * sum_m ginv[k][m] * T[i][j][m]; coalesced store
    {
        const int kk = tid >> 5, ii = (tid >> 1) & 15, jh = (tid & 1) * 8;
        float gk[16];
        #pragma unroll
        for (int m = 0; m < 16; ++m) gk[m] = gaug[kk * 36 + 16 + m];
        float gout[8];
        #pragma unroll
        for (int q = 0; q < 8; ++q) {
            const float* Tv = &SM[(2 * ii + 1) * DD + (jh + q) * 16];
            float s = 0.0f;
            #pragma unroll
            for (int m = 0; m < 16; ++m) s = fmaf(gk[m], Tv[m], s);
            gout[q] = 0.5f * s;
        }
        float4* dst = (float4*)&out[(size_t)pt * 4096 + kk * 256 + ii * 16 + jh];
        dst[0] = *(const float4*)&gout[0];
        dst[1] = *(const float4*)&gout[4];
    }
}

extern "C" void kernel_launch(void* const* d_in, const int* in_sizes, int n_in,
                              void* d_out, int out_size, void* d_ws, size_t ws_size,
                              hipStream_t stream) {
    const float* z  = (const float*)d_in[0];
    const float* W1 = (const float*)d_in[1];
    const float* b1 = (const float*)d_in[2];
    const float* W2 = (const float*)d_in[3];
    const float* b2 = (const float*)d_in[4];
    float* out = (float*)d_out;
    const int npts = in_sizes[0] / 16;   // B*L = 8192
    christoffel_mimic<<<npts, 512, 0, stream>>>(z, W1, b1, W2, b2, out);
}

// Round 5
// 2048.678 us; speedup vs baseline: 7.1700x; 7.1700x over previous
//
#include <hip/hip_runtime.h>

// v5: bitwise arithmetic of v3 (passed, absmax 8.179e-3), restructured:
//  - 512 threads, __launch_bounds__(512,2) -> empirical 128-VGPR cap (v4's
//    arg=4 gave 64 VGPR + 76GB scratch traffic = the 15ms regression)
//  - W2 NOT staged in LDS (no block-level reuse; L2-resident, global->reg)
//  - h[33][512] computed in a separate register-light phase, lives in LDS
//  - GEMM: wave = (rowset rs = wv>>1) x (colhalf ch = wv&1); 8(9) rows x
//    2 cols/lane; ascending-j fmaf chains, KC split at 384 (OpenBLAS)
// Epilogue identical to v4 (verified bitwise vs v3).

#define HH 512
#define DD 256
#define EPSF 1e-4f
#define TWOEPS (2.0f * 1e-4f)

__global__ __launch_bounds__(512, 2)
void christoffel_v5(const float* __restrict__ z,
                    const float* __restrict__ W1,
                    const float* __restrict__ b1,
                    const float* __restrict__ W2,
                    const float* __restrict__ b2,
                    float* __restrict__ out)
{
    // hS: h[33][512] (67.6KB). After GEMM, overlay A[33][256] at [0,8448);
    // dg -> even A rows, T -> odd A rows (same scheme v4 validated).
    __shared__ __align__(16) float hS[33 * HH];
    __shared__ float gaug[16 * 36];
    __shared__ float zS[16];

    const int tid  = threadIdx.x;
    const int pt   = blockIdx.x;
    const int wv   = tid >> 6;
    const int lane = tid & 63;

    if (tid < 16) zS[tid] = z[pt * 16 + tid];
    __syncthreads();

    // ---------- Phase 1: h[e][j], j = tid, e = 0..32 (32 FD evals + central)
    {
        const int j = tid;
        float w1c[16];
        #pragma unroll
        for (int d = 0; d < 16; ++d) w1c[d] = W1[d * HH + j];
        const float b1v = b1[j];
        #pragma unroll 1
        for (int e = 0; e < 33; ++e) {
            const int p = (e < 32) ? (e >> 1) : -1;
            float a = 0.0f;
            #pragma unroll
            for (int d = 0; d < 16; ++d) {
                float zd = zS[d];
                if (d == p) zd = (e & 1) ? (zd - EPSF) : (zd + EPSF);
                a = fmaf(zd, w1c[d], a);    // ascending-d chain (sgemm K=16)
            }
            a = a + b1v;                     // separate bias add
            hS[e * HH + j] = (float)tanh((double)a);  // f64 tanh -> f32
        }
    }
    __syncthreads();

    // ---------- Phase 2: A = h @ W2 (+b2), ascending-j chains, KC split 384
    const int rs = wv >> 1;                 // row-set 0..3 (rows rs*8..rs*8+7)
    const int ch = wv & 1;                  // column half
    const int c2 = ch * 128 + lane * 2;     // 2 cols per lane
    const int nr = (rs == 3) ? 9 : 8;       // row-set 3 also owns central (row 32)
    const int e0 = rs * 8;

    float acc1[9][2] = {}, acc2[9][2] = {};

    auto gemm4 = [&](int j0, float (&A)[9][2]) {
        float2 w2v[4];
        #pragma unroll
        for (int q = 0; q < 4; ++q)
            w2v[q] = *(const float2*)&W2[(j0 + q) * DD + c2];
        float4 hv[9];
        #pragma unroll
        for (int r = 0; r < 9; ++r)
            if (r < nr)
                hv[r] = *(const float4*)&hS[(r < 8 ? e0 + r : 32) * HH + j0];
        #pragma unroll
        for (int q = 0; q < 4; ++q) {       // ascending j within group
            #pragma unroll
            for (int r = 0; r < 9; ++r) {
                if (r < nr) {
                    const float hq = (q == 0) ? hv[r].x : (q == 1) ? hv[r].y
                                   : (q == 2) ? hv[r].z : hv[r].w;
                    A[r][0] = fmaf(hq, w2v[q].x, A[r][0]);
                    A[r][1] = fmaf(hq, w2v[q].y, A[r][1]);
                }
            }
        }
    };

    #pragma unroll 1
    for (int jg = 0; jg < 96; ++jg)  gemm4(jg * 4, acc1);   // k = 0..383
    #pragma unroll 1
    for (int jg = 96; jg < 128; ++jg) gemm4(jg * 4, acc2);  // k = 384..511
    __syncthreads();                    // all h reads done

    // ---------- A writeback: fl(S1+S2)+b2 -> A[e][256] overlay at hS[0..8448)
    {
        #pragma unroll
        for (int r = 0; r < 9; ++r) {
            if (r < nr) {
                const int e = (r < 8) ? (e0 + r) : 32;
                float2 av;
                av.x = (acc1[r][0] + acc2[r][0]) + b2[c2];
                av.y = (acc1[r][1] + acc2[r][1]) + b2[c2 + 1];
                *(float2*)&hS[e * DD + c2] = av;
            }
        }
    }
    __syncthreads();

    // ---------- central gram -> gaug = [g | I]
    if (tid < 256) {
        const int m = tid >> 4, n = tid & 15;
        const float* AC = &hS[32 * DD];
        float s = 0.0f;
        #pragma unroll
        for (int k = 0; k < 16; ++k) s = fmaf(AC[m * 16 + k], AC[n * 16 + k], s);
        if (m == n) s = s + 1.0f;
        gaug[m * 36 + n]      = s;
        gaug[m * 36 + 16 + n] = (m == n) ? 1.0f : 0.0f;
    }

    // ---------- dg[p] = (gram(A2p)-gram(A2p+1))/2eps, in place over row 2p
    {
        const int ph = tid >> 8, m = (tid >> 4) & 15, n = tid & 15;
        #pragma unroll 1
        for (int pp = 0; pp < 8; ++pp) {
            const int p = pp * 2 + ph;
            const float* Ap = &hS[(2 * p) * DD];
            const float* Am = &hS[(2 * p + 1) * DD];
            float sp = 0.0f, sm = 0.0f;
            #pragma unroll
            for (int k = 0; k < 16; ++k) sp = fmaf(Ap[m * 16 + k], Ap[n * 16 + k], sp);
            #pragma unroll
            for (int k = 0; k < 16; ++k) sm = fmaf(Am[m * 16 + k], Am[n * 16 + k], sm);
            if (m == n) { sp = sp + 1.0f; sm = sm + 1.0f; }
            const float dgv = (sp - sm) / TWOEPS;
            __syncthreads();                 // all reads done before in-place write
            hS[(2 * p) * DD + m * 16 + n] = dgv;
        }
    }
    __syncthreads();

    // ---------- Gauss-Jordan inverse of central g (one col per thread)
    {
        const int i = tid >> 5, c = tid & 31;
        #pragma unroll 1
        for (int k = 0; k < 16; ++k) {
            const float pv = gaug[k * 36 + k];
            const float f  = gaug[i * 36 + k];
            const float rk = gaug[k * 36 + c];
            const float gi = gaug[i * 36 + c];
            __syncthreads();
            const float invp = 1.0f / pv;
            gaug[i * 36 + c] = (i == k) ? (rk * invp) : (gi - (f * invp) * rk);
            __syncthreads();
        }
    }

    // ---------- T[i][j][m] = dg_i[j,m] + dg_j[i,m] - dg_m[i,j] -> odd rows
    {
        const int i = tid >> 5, j = (tid >> 1) & 15, mh = (tid & 1) * 8;
        float tv[8];
        #pragma unroll
        for (int q = 0; q < 8; ++q) {
            const int m = mh + q;
            tv[q] = hS[(2 * i) * DD + j * 16 + m]
                  + hS[(2 * j) * DD + i * 16 + m]
                  - hS[(2 * m) * DD + i * 16 + j];
        }
        #pragma unroll
        for (int q = 0; q < 8; ++q)
            hS[(2 * i + 1) * DD + j * 16 + mh + q] = tv[q];
    }
    __syncthreads();

    // ---------- Gamma[k][i][j] = 0.5 * sum_m ginv[k][m]*T[i][j][m]; store
    {
        const int kk = tid >> 5, ii = (tid >> 1) & 15, jh = (tid & 1) * 8;
        float gk[16];
        #pragma unroll
        for (int m = 0; m < 16; ++m) gk[m] = gaug[kk * 36 + 16 + m];
        float gout[8];
        #pragma unroll
        for (int q = 0; q < 8; ++q) {
            const float* Tv = &hS[(2 * ii + 1) * DD + (jh + q) * 16];
            float s = 0.0f;
            #pragma unroll
            for (int m = 0; m < 16; ++m) s = fmaf(gk[m], Tv[m], s);
            gout[q] = 0.5f * s;
        }
        float4* dst = (float4*)&out[(size_t)pt * 4096 + kk * 256 + ii * 16 + jh];
        dst[0] = *(const float4*)&gout[0];
        dst[1] = *(const float4*)&gout[4];
    }
}

extern "C" void kernel_launch(void* const* d_in, const int* in_sizes, int n_in,
                              void* d_out, int out_size, void* d_ws, size_t ws_size,
                              hipStream_t stream) {
    const float* z  = (const float*)d_in[0];
    const float* W1 = (const float*)d_in[1];
    const float* b1 = (const float*)d_in[2];
    const float* W2 = (const float*)d_in[3];
    const float* b2 = (const float*)d_in[4];
    float* out = (float*)d_out;
    const int npts = in_sizes[0] / 16;   // B*L = 8192
    christoffel_v5<<<npts, 512, 0, stream>>>(z, W1, b1, W2, b2, out);
}